// Round 6
// baseline (194.239 us; speedup 1.0000x reference)
//
#include <hip/hip_runtime.h>
#include <math.h>

// Problem constants (fixed shapes from setup_inputs)
#define B_ 32
#define C_ 192
#define H_ 64
#define W_ 64
#define L_ 4096          // H_*W_
#define L4_ 1024         // L_/4
#define NTHREADS 256
#define PER_THREAD 16    // L_ / NTHREADS
#define ROWS_DEEP 4      // rows per block in the deep-ILP variant
#define BHALF 16         // batches per variant

typedef float  f32x4 __attribute__((ext_vector_type(4)));  // clang-native vec4

// ---------------------------------------------------------------------------
// Kernel 1: per-batch stats + keep mask + stable compaction scan.
// UNCHANGED from verified version (absmax == 0) — do not touch numerics.
// ---------------------------------------------------------------------------
__global__ __launch_bounds__(NTHREADS) void stats_scan_kernel(
    const float* __restrict__ delta,  // [B, L]
    int*  __restrict__ src_idx,       // [B, L] out: src token for dest slot d
    int*  __restrict__ counts,        // [B]
    float* __restrict__ thetas)       // [B]
{
  const int b = blockIdx.x;
  const int t = threadIdx.x;
  const int lane = t & 63;
  const int wid  = t >> 6;            // 4 waves of 64

  __shared__ float  smin[4], smax[4];
  __shared__ float  s_lo, s_rng, s_theta;
  __shared__ double dsum[4], dsum2[4];
  __shared__ int    wsum[4];

  const float* dp = delta + (size_t)b * L_;

  float a[PER_THREAD];
  const float4* d4 = (const float4*)dp;
  #pragma unroll
  for (int i = 0; i < 4; ++i) {
    float4 v = d4[t * 4 + i];
    a[i*4+0] = fabsf(v.x); a[i*4+1] = fabsf(v.y);
    a[i*4+2] = fabsf(v.z); a[i*4+3] = fabsf(v.w);
  }

  // ---- min/max reduce (f32, exact) ----
  float lmin = a[0], lmax = a[0];
  #pragma unroll
  for (int i = 1; i < PER_THREAD; ++i) {
    lmin = fminf(lmin, a[i]);
    lmax = fmaxf(lmax, a[i]);
  }
  #pragma unroll
  for (int off = 32; off; off >>= 1) {
    lmin = fminf(lmin, __shfl_down(lmin, off, 64));
    lmax = fmaxf(lmax, __shfl_down(lmax, off, 64));
  }
  if (lane == 0) { smin[wid] = lmin; smax[wid] = lmax; }
  __syncthreads();
  if (t == 0) {
    float lo = fminf(fminf(smin[0], smin[1]), fminf(smin[2], smin[3]));
    float hi = fmaxf(fmaxf(smax[0], smax[1]), fmaxf(smax[2], smax[3]));
    s_lo  = lo;
    s_rng = fmaxf(hi - lo, 1e-3f);   // clamp_min(0.001), f32 like reference
  }
  __syncthreads();
  const float lo  = s_lo;
  const float rng = s_rng;

  double s = 0.0, s2 = 0.0;
  #pragma unroll
  for (int i = 0; i < PER_THREAD; ++i) {
    float imp = (a[i] - lo) / rng;   // f32 IEEE div, matches reference
    a[i] = imp;
    s  += (double)imp;
    s2 += (double)imp * (double)imp;
  }
  #pragma unroll
  for (int off = 32; off; off >>= 1) {
    s  += __shfl_down(s,  off, 64);
    s2 += __shfl_down(s2, off, 64);
  }
  if (lane == 0) { dsum[wid] = s; dsum2[wid] = s2; }
  __syncthreads();
  if (t == 0) {
    double S  = dsum[0]  + dsum[1]  + dsum[2]  + dsum[3];
    double S2 = dsum2[0] + dsum2[1] + dsum2[2] + dsum2[3];
    double mu  = S / (double)L_;
    double var = (S2 - S * S / (double)L_) / (double)(L_ - 1);  // ddof=1
    if (var < 0.0) var = 0.0;
    double sigma = sqrt(var);
    s_theta = (float)(mu - 0.1 * sigma);
  }
  __syncthreads();
  const float theta = s_theta;

  int flags = 0, cnt = 0;
  #pragma unroll
  for (int i = 0; i < PER_THREAD; ++i) {
    int k = (a[i] >= theta) ? 1 : 0;
    cnt += k;
    flags |= (k << i);
  }
  int inc = cnt;
  #pragma unroll
  for (int off = 1; off < 64; off <<= 1) {
    int y = __shfl_up(inc, off, 64);
    if (lane >= off) inc += y;
  }
  if (lane == 63) wsum[wid] = inc;
  __syncthreads();
  int base = inc - cnt;                       // exclusive within wave
  #pragma unroll
  for (int w = 0; w < 4; ++w)
    if (w < wid) base += wsum[w];             // add preceding waves

  int* sb = src_idx + (size_t)b * L_;
  int p = base;
  #pragma unroll
  for (int i = 0; i < PER_THREAD; ++i) {
    if ((flags >> i) & 1) { sb[p++] = t * PER_THREAD + i; }
  }
  if (t == NTHREADS - 1) {
    counts[b] = base + cnt;   // total kept
    thetas[b] = theta;
  }
}

// ---------------------------------------------------------------------------
// Kernel 2a: DEEP-ILP direct-global gather (batches [0, BHALF)).
// 768 blocks x 4 same-batch rows. idx loaded ONCE per block; then 64
// independent gather loads + 16 stores per thread with zero barriers —
// one long VMEM stream per wave so latency amortizes across rows.
// ---------------------------------------------------------------------------
__global__ __launch_bounds__(NTHREADS) void gather_deep(
    const float* __restrict__ x,        // [B, C, L]
    const int*  __restrict__ src_idx,   // [B, L]
    const int*  __restrict__ counts,    // [B]
    const float* __restrict__ thetas,   // [B]
    float* __restrict__ out,            // [B, C, L]
    float* __restrict__ out_tail)       // 2 floats: keep_ratio, theta_mean
{
  const int blk = blockIdx.x;           // [0, BHALF*C_/ROWS_DEEP) = [0, 768)
  const int bc0 = blk * ROWS_DEEP;      // first row (global bc), all 4 same b
  const int b   = bc0 / C_;             // [0, 16)
  const int t   = threadIdx.x;

  // ---- folded finalize: block 0, wave 0 only ----
  if (blk == 0 && t < 64) {
    float cc = (t < B_) ? (float)counts[t] : 0.0f;
    float th = (t < B_) ? thetas[t]        : 0.0f;
    #pragma unroll
    for (int off = 32; off; off >>= 1) {
      cc += __shfl_down(cc, off, 64);
      th += __shfl_down(th, off, 64);
    }
    if (t == 0) {
      out_tail[0] = (cc / (float)B_) / (float)L_;  // keep_ratio
      out_tail[1] = th / (float)B_;                // theta_mean
    }
  }

  const int cnt = counts[b];

  // idx once per block; pre-mask so garbage (d >= cnt) indices stay in-row
  int sidx[PER_THREAD];
  {
    const int4* s4b = (const int4*)(src_idx + (size_t)b * L_);
    #pragma unroll
    for (int i = 0; i < 4; ++i) {
      const int4 s = s4b[t + NTHREADS * i];
      sidx[i*4+0] = s.x & (L_ - 1);
      sidx[i*4+1] = s.y & (L_ - 1);
      sidx[i*4+2] = s.z & (L_ - 1);
      sidx[i*4+3] = s.w & (L_ - 1);
    }
  }

  // 4 rows, fully unrolled, no sync: 64 gather loads + 16 float4 stores per
  // thread form one deep independent VMEM stream.
  #pragma unroll
  for (int r = 0; r < ROWS_DEEP; ++r) {
    const float* xr = x   + (size_t)(bc0 + r) * L_;
    f32x4*       o4 = (f32x4*)(out + (size_t)(bc0 + r) * L_);
    #pragma unroll
    for (int i = 0; i < 4; ++i) {
      const int j  = t + NTHREADS * i;  // float4 dest index in [0, 1024)
      const int d0 = j * 4;
      f32x4 rr = {0.0f, 0.0f, 0.0f, 0.0f};
      if (d0 < cnt) {                   // uniform for all-tail waves
        rr.x = xr[sidx[i*4+0]];
        rr.y = (d0 + 1 < cnt) ? xr[sidx[i*4+1]] : 0.0f;
        rr.z = (d0 + 2 < cnt) ? xr[sidx[i*4+2]] : 0.0f;
        rr.w = (d0 + 3 < cnt) ? xr[sidx[i*4+3]] : 0.0f;
      }
      o4[j] = rr;
    }
  }
}

// ---------------------------------------------------------------------------
// Kernel 2b: round-5 direct gather, CONTROL (batches [BHALF, 32)).
// One block per row, 3072 blocks. Unchanged structure.
// ---------------------------------------------------------------------------
__global__ __launch_bounds__(NTHREADS) void gather_direct(
    const float* __restrict__ x,        // [B, C, L]
    const int*  __restrict__ src_idx,   // [B, L]
    const int*  __restrict__ counts,    // [B]
    float* __restrict__ out)            // [B, C, L]
{
  const int bc = BHALF * C_ + blockIdx.x;   // global row in [3072, 6144)
  const int b  = bc / C_;
  const int t  = threadIdx.x;

  const size_t rowbase = (size_t)bc * L_;
  const float* xr  = x + rowbase;
  const int    cnt = counts[b];
  const int4*  s4b = (const int4*)(src_idx + (size_t)b * L_);
  f32x4*       o4  = (f32x4*)(out + rowbase);

  #pragma unroll
  for (int i = 0; i < 4; ++i) {
    const int j  = t + NTHREADS * i;    // float4 dest index in [0, 1024)
    const int d0 = j * 4;
    f32x4 r = {0.0f, 0.0f, 0.0f, 0.0f};
    if (d0 < cnt) {                     // uniform for all-tail waves
      const int4 s = s4b[j];
      r.x = xr[s.x & (L_ - 1)];
      r.y = (d0 + 1 < cnt) ? xr[s.y & (L_ - 1)] : 0.0f;
      r.z = (d0 + 2 < cnt) ? xr[s.z & (L_ - 1)] : 0.0f;
      r.w = (d0 + 3 < cnt) ? xr[s.w & (L_ - 1)] : 0.0f;
    }
    o4[j] = r;
  }
}

// ---------------------------------------------------------------------------
extern "C" void kernel_launch(void* const* d_in, const int* in_sizes, int n_in,
                              void* d_out, int out_size, void* d_ws, size_t ws_size,
                              hipStream_t stream) {
  const float* x     = (const float*)d_in[0];   // [32,192,64,64]
  const float* delta = (const float*)d_in[1];   // [32,1,64,64]
  float* out = (float*)d_out;                   // y (B*C*L) ++ keep_ratio ++ theta_mean

  // workspace layout (unchanged)
  int*   src_idx = (int*)d_ws;                                   // B*L ints = 512 KB
  int*   counts  = (int*)((char*)d_ws + (size_t)B_ * L_ * 4);    // 32 ints
  float* thetas  = (float*)((char*)d_ws + (size_t)B_ * L_ * 4 + 128);

  const size_t y_elems = (size_t)B_ * C_ * L_;  // 25,165,824
  float* out_tail = out + y_elems;

  stats_scan_kernel<<<B_, NTHREADS, 0, stream>>>(delta, src_idx, counts, thetas);

  // Deep-ILP half: batches 0..15 -> 16*192/4 = 768 blocks
  gather_deep<<<BHALF * C_ / ROWS_DEEP, NTHREADS, 0, stream>>>(
      x, src_idx, counts, thetas, out, out_tail);
  // Control half: batches 16..31 -> 3072 one-row blocks (round-5 structure)
  gather_direct<<<BHALF * C_, NTHREADS, 0, stream>>>(x, src_idx, counts, out);
}

// Round 7
// 190.604 us; speedup vs baseline: 1.0191x; 1.0191x over previous
//
#include <hip/hip_runtime.h>
#include <math.h>

// Problem constants (fixed shapes from setup_inputs)
#define B_ 32
#define C_ 192
#define H_ 64
#define W_ 64
#define L_ 4096          // H_*W_
#define NTHREADS 256
#define PER_THREAD 16    // L_ / NTHREADS
#define CPB 8            // rows per producer/consumer block
#define SLOTS 3          // LDS ring slots (48 KB -> 3 blocks/CU)

typedef float  f32x4 __attribute__((ext_vector_type(4)));  // clang-native vec4

// ---------------------------------------------------------------------------
// Kernel 1: per-batch stats + keep mask + stable compaction scan.
// UNCHANGED from verified version (absmax == 0) — do not touch numerics.
// ---------------------------------------------------------------------------
__global__ __launch_bounds__(NTHREADS) void stats_scan_kernel(
    const float* __restrict__ delta,  // [B, L]
    int*  __restrict__ src_idx,       // [B, L] out: src token for dest slot d
    int*  __restrict__ counts,        // [B]
    float* __restrict__ thetas)       // [B]
{
  const int b = blockIdx.x;
  const int t = threadIdx.x;
  const int lane = t & 63;
  const int wid  = t >> 6;            // 4 waves of 64

  __shared__ float  smin[4], smax[4];
  __shared__ float  s_lo, s_rng, s_theta;
  __shared__ double dsum[4], dsum2[4];
  __shared__ int    wsum[4];

  const float* dp = delta + (size_t)b * L_;

  float a[PER_THREAD];
  const float4* d4 = (const float4*)dp;
  #pragma unroll
  for (int i = 0; i < 4; ++i) {
    float4 v = d4[t * 4 + i];
    a[i*4+0] = fabsf(v.x); a[i*4+1] = fabsf(v.y);
    a[i*4+2] = fabsf(v.z); a[i*4+3] = fabsf(v.w);
  }

  // ---- min/max reduce (f32, exact) ----
  float lmin = a[0], lmax = a[0];
  #pragma unroll
  for (int i = 1; i < PER_THREAD; ++i) {
    lmin = fminf(lmin, a[i]);
    lmax = fmaxf(lmax, a[i]);
  }
  #pragma unroll
  for (int off = 32; off; off >>= 1) {
    lmin = fminf(lmin, __shfl_down(lmin, off, 64));
    lmax = fmaxf(lmax, __shfl_down(lmax, off, 64));
  }
  if (lane == 0) { smin[wid] = lmin; smax[wid] = lmax; }
  __syncthreads();
  if (t == 0) {
    float lo = fminf(fminf(smin[0], smin[1]), fminf(smin[2], smin[3]));
    float hi = fmaxf(fmaxf(smax[0], smax[1]), fmaxf(smax[2], smax[3]));
    s_lo  = lo;
    s_rng = fmaxf(hi - lo, 1e-3f);   // clamp_min(0.001), f32 like reference
  }
  __syncthreads();
  const float lo  = s_lo;
  const float rng = s_rng;

  double s = 0.0, s2 = 0.0;
  #pragma unroll
  for (int i = 0; i < PER_THREAD; ++i) {
    float imp = (a[i] - lo) / rng;   // f32 IEEE div, matches reference
    a[i] = imp;
    s  += (double)imp;
    s2 += (double)imp * (double)imp;
  }
  #pragma unroll
  for (int off = 32; off; off >>= 1) {
    s  += __shfl_down(s,  off, 64);
    s2 += __shfl_down(s2, off, 64);
  }
  if (lane == 0) { dsum[wid] = s; dsum2[wid] = s2; }
  __syncthreads();
  if (t == 0) {
    double S  = dsum[0]  + dsum[1]  + dsum[2]  + dsum[3];
    double S2 = dsum2[0] + dsum2[1] + dsum2[2] + dsum2[3];
    double mu  = S / (double)L_;
    double var = (S2 - S * S / (double)L_) / (double)(L_ - 1);  // ddof=1
    if (var < 0.0) var = 0.0;
    double sigma = sqrt(var);
    s_theta = (float)(mu - 0.1 * sigma);
  }
  __syncthreads();
  const float theta = s_theta;

  int flags = 0, cnt = 0;
  #pragma unroll
  for (int i = 0; i < PER_THREAD; ++i) {
    int k = (a[i] >= theta) ? 1 : 0;
    cnt += k;
    flags |= (k << i);
  }
  int inc = cnt;
  #pragma unroll
  for (int off = 1; off < 64; off <<= 1) {
    int y = __shfl_up(inc, off, 64);
    if (lane >= off) inc += y;
  }
  if (lane == 63) wsum[wid] = inc;
  __syncthreads();
  int base = inc - cnt;                       // exclusive within wave
  #pragma unroll
  for (int w = 0; w < 4; ++w)
    if (w < wid) base += wsum[w];             // add preceding waves

  int* sb = src_idx + (size_t)b * L_;
  int p = base;
  #pragma unroll
  for (int i = 0; i < PER_THREAD; ++i) {
    if ((flags >> i) & 1) { sb[p++] = t * PER_THREAD + i; }
  }
  if (t == NTHREADS - 1) {
    counts[b] = base + cnt;   // total kept
    thetas[b] = theta;
  }
}

// ---------------------------------------------------------------------------
// Kernel 2: PRODUCER/CONSUMER wave-specialized gather.
// One block per 8 same-batch rows: 768 blocks = exactly 3/CU, 48 KB LDS ring.
//   waves 0-1 (producers): pure read stream. Per row: 8 back-to-back dwordx4
//     global loads -> LDS slot, then signal ready[slot] (seq number).
//   waves 2-3 (consumers): idx + keep-mask held in registers (loaded once);
//     poll ready, LDS-gather, pure coalesced float4 store stream, signal done.
// No block-wide barriers in the steady state -> no vmcnt(0) drains; the read
// and write streams are each driven by dedicated waves (m13-copy / fill-like).
// Flag protocol: monotone seq numbers; LDS ops complete in-order per wave
// (lgkmcnt), fenced with s_waitcnt lgkmcnt(0) + compiler memory clobbers.
// ---------------------------------------------------------------------------
__global__ __launch_bounds__(NTHREADS) void gather_pc(
    const float* __restrict__ x,        // [B, C, L]
    const int*  __restrict__ src_idx,   // [B, L]
    const int*  __restrict__ counts,    // [B]
    const float* __restrict__ thetas,   // [B]
    float* __restrict__ out,            // [B, C, L]
    float* __restrict__ out_tail)       // 2 floats: keep_ratio, theta_mean
{
  __shared__ float slotbuf[SLOTS][L_];      // 48 KB ring
  __shared__ volatile int ready[SLOTS][2];  // per producer wave
  __shared__ volatile int done_[SLOTS][2];  // per consumer wave

  const int blk  = blockIdx.x;          // [0, B_*C_/CPB) = [0, 768)
  const int bc0  = blk * CPB;           // first row; all CPB rows same batch
  const int b    = bc0 / C_;
  const int t    = threadIdx.x;
  const int w    = t >> 6;              // wave 0..3
  const int lane = t & 63;

  // flag init: ready=-1; done_[s][*] = s - SLOTS (first fill of slot s is
  // row r=s, whose free-condition is done_ >= s - SLOTS -> passes).
  if (t < SLOTS) {
    ready[t][0] = -1;      ready[t][1] = -1;
    done_[t][0] = t - SLOTS; done_[t][1] = t - SLOTS;
  }

  // ---- folded finalize: block 0, wave 0 only (before the barrier) ----
  if (blk == 0 && t < 64) {
    float cc = (t < B_) ? (float)counts[t] : 0.0f;
    float th = (t < B_) ? thetas[t]        : 0.0f;
    #pragma unroll
    for (int off = 32; off; off >>= 1) {
      cc += __shfl_down(cc, off, 64);
      th += __shfl_down(th, off, 64);
    }
    if (t == 0) {
      out_tail[0] = (cc / (float)B_) / (float)L_;  // keep_ratio
      out_tail[1] = th / (float)B_;                // theta_mean
    }
  }

  __syncthreads();   // one-time: flags visible to all waves

  if (w < 2) {
    // ======================= PRODUCER (waves 0,1) =======================
    // wave w streams float4 range [w*512, w*512+512) of each row.
    const int base4 = w * 512 + lane;
    #pragma unroll
    for (int r = 0; r < CPB; ++r) {
      const int s = r % SLOTS;
      // wait until both consumers finished the row previously in this slot
      while (done_[s][0] < r - SLOTS || done_[s][1] < r - SLOTS)
        __builtin_amdgcn_s_sleep(1);
      asm volatile("" ::: "memory");
      const float4* xr = (const float4*)(x + (size_t)(bc0 + r) * L_);
      float4 st[8];
      #pragma unroll
      for (int i = 0; i < 8; ++i) st[i] = xr[base4 + 64 * i];
      float4* dst = (float4*)&slotbuf[s][0];
      #pragma unroll
      for (int i = 0; i < 8; ++i) dst[base4 + 64 * i] = st[i];
      // LDS writes complete (in-order) before the flag becomes visible
      asm volatile("s_waitcnt lgkmcnt(0)" ::: "memory");
      if (lane == 0) ready[s][w] = r;
    }
  } else {
    // ======================= CONSUMER (waves 2,3) =======================
    const int cw  = w - 2;              // consumer 0,1: dest half [cw*512,+512)
    const int cnt = counts[b];

    // idx + keep mask once per block, reused for all CPB rows.
    int sidx[32];
    unsigned kmask = 0;
    const int4* s4b = (const int4*)(src_idx + (size_t)b * L_);
    #pragma unroll
    for (int i = 0; i < 8; ++i) {
      const int j  = cw * 512 + lane + 64 * i;   // float4 dest index
      const int4 s4 = s4b[j];
      sidx[i*4+0] = s4.x & (L_ - 1);   // pre-mask: garbage idx stays in-row
      sidx[i*4+1] = s4.y & (L_ - 1);
      sidx[i*4+2] = s4.z & (L_ - 1);
      sidx[i*4+3] = s4.w & (L_ - 1);
      const int d0 = j * 4;
      kmask |= (d0     < cnt ? 1u : 0u) << (i*4+0);
      kmask |= (d0 + 1 < cnt ? 1u : 0u) << (i*4+1);
      kmask |= (d0 + 2 < cnt ? 1u : 0u) << (i*4+2);
      kmask |= (d0 + 3 < cnt ? 1u : 0u) << (i*4+3);
    }

    #pragma unroll
    for (int r = 0; r < CPB; ++r) {
      const int s = r % SLOTS;
      while (ready[s][0] < r || ready[s][1] < r)
        __builtin_amdgcn_s_sleep(1);
      asm volatile("" ::: "memory");   // no hoisting of ds_reads above poll
      const float* row = &slotbuf[s][0];
      f32x4* o4 = (f32x4*)(out + (size_t)(bc0 + r) * L_);
      #pragma unroll
      for (int i = 0; i < 8; ++i) {
        const int j = cw * 512 + lane + 64 * i;
        f32x4 rr;
        rr.x = ((kmask >> (i*4+0)) & 1) ? row[sidx[i*4+0]] : 0.0f;
        rr.y = ((kmask >> (i*4+1)) & 1) ? row[sidx[i*4+1]] : 0.0f;
        rr.z = ((kmask >> (i*4+2)) & 1) ? row[sidx[i*4+2]] : 0.0f;
        rr.w = ((kmask >> (i*4+3)) & 1) ? row[sidx[i*4+3]] : 0.0f;
        o4[j] = rr;                    // coalesced 1 KB/wave-instr
      }
      // ds_reads retired (values feed the issued stores); flag after reads
      asm volatile("s_waitcnt lgkmcnt(0)" ::: "memory");
      if (lane == 0) done_[s][cw] = r;
    }
  }
}

// ---------------------------------------------------------------------------
extern "C" void kernel_launch(void* const* d_in, const int* in_sizes, int n_in,
                              void* d_out, int out_size, void* d_ws, size_t ws_size,
                              hipStream_t stream) {
  const float* x     = (const float*)d_in[0];   // [32,192,64,64]
  const float* delta = (const float*)d_in[1];   // [32,1,64,64]
  float* out = (float*)d_out;                   // y (B*C*L) ++ keep_ratio ++ theta_mean

  // workspace layout (unchanged)
  int*   src_idx = (int*)d_ws;                                   // B*L ints = 512 KB
  int*   counts  = (int*)((char*)d_ws + (size_t)B_ * L_ * 4);    // 32 ints
  float* thetas  = (float*)((char*)d_ws + (size_t)B_ * L_ * 4 + 128);

  const size_t y_elems = (size_t)B_ * C_ * L_;  // 25,165,824
  float* out_tail = out + y_elems;

  stats_scan_kernel<<<B_, NTHREADS, 0, stream>>>(delta, src_idx, counts, thetas);
  gather_pc<<<B_ * C_ / CPB, NTHREADS, 0, stream>>>(x, src_idx, counts, thetas,
                                                    out, out_tail);
}